// Round 8
// baseline (902.584 us; speedup 1.0000x reference)
//
#include <hip/hip_runtime.h>
#include <math.h>

// ---------------- problem constants ----------------
#define E_DIM    2048
#define E4       512          // E_DIM / 4
#define NHEAD    16
#define T_CACHE  8192
#define TT       8193         // T_CACHE + 1 (includes new token)
#define ATT_STRIDE 8224       // padded per-head stride for score buffer
#define ATT_SCALE 0.08838834764831845f   // 1/sqrt(128)
#define CHUNK    16
#define NCHUNK   513          // ceil(8193/16)
#define RMS_EPS  1e-5f
#define VOCAB    50257

__device__ __forceinline__ float dot4(const float4 a, const float4 b) {
    return fmaf(a.x, b.x, fmaf(a.y, b.y, fmaf(a.z, b.z, a.w * b.w)));
}

__device__ __forceinline__ float waveAllSum(float v) {
#pragma unroll
    for (int off = 32; off >= 1; off >>= 1)
        v += __shfl_xor(v, off, 64);
    return v;
}

// ---------------- templated wave-per-row matvec ----------------
template<int K4, bool RELU, bool ADD>
__global__ __launch_bounds__(256)
void matvec_kernel(const float* __restrict__ W, const float* __restrict__ x,
                   const float* __restrict__ add, float* __restrict__ out,
                   int rows) {
    const int wid  = threadIdx.x >> 6;
    const int lane = threadIdx.x & 63;
    const int r    = blockIdx.x * 4 + wid;
    if (r >= rows) return;
    const float4* __restrict__ Wr = (const float4*)(W + (size_t)r * (size_t)(K4 * 4));
    const float4* __restrict__ x4 = (const float4*)x;
    constexpr int ITER = K4 / 64;                 // 8 for E, 32 for 4E
    float acc0 = 0.f, acc1 = 0.f, acc2 = 0.f, acc3 = 0.f;
#pragma unroll
    for (int i = 0; i < ITER; i += 4) {
        acc0 += dot4(Wr[(i + 0) * 64 + lane], x4[(i + 0) * 64 + lane]);
        acc1 += dot4(Wr[(i + 1) * 64 + lane], x4[(i + 1) * 64 + lane]);
        acc2 += dot4(Wr[(i + 2) * 64 + lane], x4[(i + 2) * 64 + lane]);
        acc3 += dot4(Wr[(i + 3) * 64 + lane], x4[(i + 3) * 64 + lane]);
    }
    float acc = waveAllSum((acc0 + acc1) + (acc2 + acc3));
    if (lane == 0) {
        float v = acc;
        if (ADD) v += add[r];
        if (RELU) v = fmaxf(v, 0.f);
        out[r] = v;
    }
}

// ---------------- fused RMS + matvec: out[r] = relu?(rsqrt(mean(x^2)+eps) * dot(W[r],x)) ----------------
// dot(W, x*s) == s * dot(W, x): each wave computes both dot and sumsq from the
// same x load stream; removes the separate 1-block rms kernel.
template<int K4, bool RELU>
__global__ __launch_bounds__(256)
void rms_matvec_kernel(const float* __restrict__ W, const float* __restrict__ x,
                       float* __restrict__ out, int rows) {
    const int wid  = threadIdx.x >> 6;
    const int lane = threadIdx.x & 63;
    const int r    = blockIdx.x * 4 + wid;
    if (r >= rows) return;
    const float4* __restrict__ Wr = (const float4*)(W + (size_t)r * (size_t)(K4 * 4));
    const float4* __restrict__ x4 = (const float4*)x;
    constexpr int ITER = K4 / 64;
    float acc = 0.f, ss = 0.f;
#pragma unroll
    for (int i = 0; i < ITER; ++i) {
        const float4 xv = x4[i * 64 + lane];
        acc += dot4(Wr[i * 64 + lane], xv);
        ss  += dot4(xv, xv);
    }
    acc = waveAllSum(acc);
    ss  = waveAllSum(ss);
    if (lane == 0) {
        const float s = rsqrtf(ss / (float)(K4 * 4) + RMS_EPS);
        float v = s * acc;
        if (RELU) v = fmaxf(v, 0.f);
        out[r] = v;
    }
}

// ---------------- fused embed + double-RMS + q/k/v projection ----------------
// Every block recomputes embed + double RMS into LDS (wte/wpe rows are L2/L3-hot),
// then dots its 4 weight rows against LDS-resident x. Block 0 also writes x_res
// (post-first-RMS activation) for the wo residual-add later.
__global__ __launch_bounds__(256)
void qkv_fused_kernel(const int* __restrict__ tok, const int* __restrict__ pos,
                      const float* __restrict__ wte, const float* __restrict__ wpe,
                      const float* __restrict__ wq, const float* __restrict__ wk,
                      const float* __restrict__ wv, float* __restrict__ x_res,
                      float* __restrict__ q, float* __restrict__ k, float* __restrict__ v) {
    __shared__ float red[4];
    __shared__ float4 xs4[E4];                     // 8 KB: double-normed x
    const int tid  = threadIdx.x;
    const int wid  = tid >> 6, lane = tid & 63;

    const int t = tok[0], p = pos[0];
    const float4* a = (const float4*)(wte + (size_t)t * E_DIM);
    const float4* b = (const float4*)(wpe + (size_t)p * E_DIM);
    float4 v0 = a[tid];       const float4 w0 = b[tid];
    float4 v1 = a[tid + 256]; const float4 w1 = b[tid + 256];
    v0.x += w0.x; v0.y += w0.y; v0.z += w0.z; v0.w += w0.w;
    v1.x += w1.x; v1.y += w1.y; v1.z += w1.z; v1.w += w1.w;

    float ss = dot4(v0, v0) + dot4(v1, v1);
    ss = waveAllSum(ss);
    if (lane == 0) red[wid] = ss;
    __syncthreads();
    const float tot = red[0] + red[1] + red[2] + red[3];
    const float s1  = rsqrtf(tot / E_DIM + RMS_EPS);
    // second RMS of (x*s1): mean = tot*s1^2/E — no second reduction needed
    const float s2  = rsqrtf(tot * s1 * s1 / E_DIM + RMS_EPS);
    const float s12 = s1 * s2;

    float4 n0, n1;
    n0.x = v0.x * s12; n0.y = v0.y * s12; n0.z = v0.z * s12; n0.w = v0.w * s12;
    n1.x = v1.x * s12; n1.y = v1.y * s12; n1.z = v1.z * s12; n1.w = v1.w * s12;
    xs4[tid] = n0; xs4[tid + 256] = n1;

    if (blockIdx.x == 0) {                         // post-first-RMS residual
        float4 r0, r1;
        r0.x = v0.x * s1; r0.y = v0.y * s1; r0.z = v0.z * s1; r0.w = v0.w * s1;
        r1.x = v1.x * s1; r1.y = v1.y * s1; r1.z = v1.z * s1; r1.w = v1.w * s1;
        float4* xr = (float4*)x_res;
        xr[tid] = r0; xr[tid + 256] = r1;
    }
    __syncthreads();

    const int gr  = blockIdx.x * 4 + wid;          // 0..6143
    const int sel = gr >> 11;                      // 0:q 1:k 2:v
    const int r   = gr & 2047;
    const float* W = (sel == 0) ? wq : (sel == 1) ? wk : wv;
    float* o       = (sel == 0) ? q  : (sel == 1) ? k  : v;
    const float4* __restrict__ Wr = (const float4*)(W + (size_t)r * E_DIM);
    float acc0 = 0.f, acc1 = 0.f, acc2 = 0.f, acc3 = 0.f;
#pragma unroll
    for (int i = 0; i < 8; i += 4) {
        acc0 += dot4(Wr[(i + 0) * 64 + lane], xs4[(i + 0) * 64 + lane]);
        acc1 += dot4(Wr[(i + 1) * 64 + lane], xs4[(i + 1) * 64 + lane]);
        acc2 += dot4(Wr[(i + 2) * 64 + lane], xs4[(i + 2) * 64 + lane]);
        acc3 += dot4(Wr[(i + 3) * 64 + lane], xs4[(i + 3) * 64 + lane]);
    }
    float acc = waveAllSum((acc0 + acc1) + (acc2 + acc3));
    if (lane == 0) o[r] = acc;
}

// ---------------- attention scores: wave per KV row t, all 16 heads ----------------
__global__ __launch_bounds__(256)
void attn_scores_kernel(const float* __restrict__ keys, const float* __restrict__ knew,
                        const float* __restrict__ q, float* __restrict__ att) {
    const int wid  = threadIdx.x >> 6;
    const int lane = threadIdx.x & 63;
    const int t    = blockIdx.x * 4 + wid;
    if (t > T_CACHE) return;                       // valid t: 0..8192
    const float4* row = (t < T_CACHE) ? (const float4*)keys + (size_t)t * E4
                                      : (const float4*)knew;
    const float4* q4 = (const float4*)q;
    float part[8];
#pragma unroll
    for (int i = 0; i < 8; ++i) {
        const int f = i * 64 + lane;               // head(f) = f/32 = 2i + (lane>>5)
        part[i] = dot4(row[f], q4[f]);
    }
#pragma unroll
    for (int i = 0; i < 8; ++i) {
        float p = part[i];
        p += __shfl_xor(p, 16, 64);                // reduce within each 32-lane half
        p += __shfl_xor(p, 8, 64);
        p += __shfl_xor(p, 4, 64);
        p += __shfl_xor(p, 2, 64);
        p += __shfl_xor(p, 1, 64);
        if (lane == 0)       att[(size_t)(2 * i)     * ATT_STRIDE + t] = p * ATT_SCALE;
        else if (lane == 32) att[(size_t)(2 * i + 1) * ATT_STRIDE + t] = p * ATT_SCALE;
    }
}

// ---------------- per-head softmax stats: single-pass online (m, s) ----------------
// sm[h] = max_t att[h,t]; sm[16+h] = 1 / sum_t exp(att[h,t]-m)
// 1024 threads, float4 loads (2 chunks/thread); tail t=8192 handled by thread 0.
__global__ __launch_bounds__(1024)
void softmax_stats_kernel(const float* __restrict__ att, float* __restrict__ sm) {
    __shared__ float redm[16], reds[16];
    const int h = blockIdx.x;
    const float* a = att + (size_t)h * ATT_STRIDE;
    const float4* a4 = (const float4*)a;
    const int tid = threadIdx.x, wid = tid >> 6, lane = tid & 63;

    float m = -1e30f, s = 0.f;
#pragma unroll
    for (int i = 0; i < 2; ++i) {                  // 2048 float4 / 1024 threads
        const float4 v = a4[i * 1024 + tid];
        const float m4 = fmaxf(fmaxf(v.x, v.y), fmaxf(v.z, v.w));
        const float s4 = expf(v.x - m4) + expf(v.y - m4)
                       + expf(v.z - m4) + expf(v.w - m4);
        const float nm = fmaxf(m, m4);
        s = s * expf(m - nm) + s4 * expf(m4 - nm);
        m = nm;
    }
    if (tid == 0) {                                // tail element t = 8192
        const float v  = a[T_CACHE];
        const float nm = fmaxf(m, v);
        s = s * expf(m - nm) + expf(v - nm);
        m = nm;
    }
#pragma unroll
    for (int off = 32; off >= 1; off >>= 1) {      // wave merge
        const float mo = __shfl_xor(m, off, 64);
        const float so = __shfl_xor(s, off, 64);
        const float nm = fmaxf(m, mo);
        s = s * expf(m - nm) + so * expf(mo - nm);
        m = nm;
    }
    if (lane == 0) { redm[wid] = m; reds[wid] = s; }
    __syncthreads();
    if (tid == 0) {                                // 16-wave merge
        float M = redm[0], S = reds[0];
#pragma unroll
        for (int j = 1; j < 16; ++j) {
            const float nm = fmaxf(M, redm[j]);
            S = S * expf(M - nm) + reds[j] * expf(redm[j] - nm);
            M = nm;
        }
        sm[h]         = M;
        sm[NHEAD + h] = 1.f / S;
    }
}

// ---------------- weighted V accumulation (softmax applied inline) ----------------
__global__ __launch_bounds__(256)
void attn_av_kernel(const float* __restrict__ values, const float* __restrict__ vnew,
                    const float* __restrict__ att, const float* __restrict__ sm,
                    float* __restrict__ part) {
    const int tid = threadIdx.x;
    const int c   = blockIdx.x;
    const int f0  = tid, f1 = tid + 256;
    const int h0  = f0 >> 5, h1 = h0 + 8;
    const float m0 = sm[h0],         m1 = sm[h1];
    const float i0 = sm[NHEAD + h0], i1 = sm[NHEAD + h1];
    float4 acc0 = {0.f, 0.f, 0.f, 0.f}, acc1 = {0.f, 0.f, 0.f, 0.f};
    const int tbase = c * CHUNK;
#pragma unroll 4
    for (int r = 0; r < CHUNK; ++r) {
        const int t = tbase + r;
        if (t >= TT) break;
        const float4* row = (t < T_CACHE) ? (const float4*)values + (size_t)t * E4
                                          : (const float4*)vnew;
        const float w0 = expf(att[(size_t)h0 * ATT_STRIDE + t] - m0) * i0;
        const float w1 = expf(att[(size_t)h1 * ATT_STRIDE + t] - m1) * i1;
        const float4 a = row[f0];
        const float4 b = row[f1];
        acc0.x = fmaf(w0, a.x, acc0.x); acc0.y = fmaf(w0, a.y, acc0.y);
        acc0.z = fmaf(w0, a.z, acc0.z); acc0.w = fmaf(w0, a.w, acc0.w);
        acc1.x = fmaf(w1, b.x, acc1.x); acc1.y = fmaf(w1, b.y, acc1.y);
        acc1.z = fmaf(w1, b.z, acc1.z); acc1.w = fmaf(w1, b.w, acc1.w);
    }
    float4* p4 = (float4*)part;
    p4[(size_t)c * E4 + f0] = acc0;
    p4[(size_t)c * E4 + f1] = acc1;
}

// ---------------- reduce partials -> x_attn ----------------
// grid = 64 blocks x 256 threads. Block b owns 8 float4-columns; threads are
// (tx = column 0..7, ty = c-stripe 0..31); 128B-contiguous loads per (c,ty)
// group; deterministic LDS tree over the 32 stripes.
__global__ __launch_bounds__(256)
void attn_reduce_kernel(const float* __restrict__ part, float* __restrict__ x_attn) {
    __shared__ float4 red[8][32];                  // 4 KB
    const int tid = threadIdx.x;
    const int tx  = tid & 7;                       // column within group
    const int ty  = tid >> 3;                      // c-stripe
    const int f   = blockIdx.x * 8 + tx;           // 0..511
    const float4* p4 = (const float4*)part;
    float4 acc = {0.f, 0.f, 0.f, 0.f};
    for (int c = ty; c < NCHUNK; c += 32) {
        const float4 v = p4[(size_t)c * E4 + f];
        acc.x += v.x; acc.y += v.y; acc.z += v.z; acc.w += v.w;
    }
    red[tx][ty] = acc;
    __syncthreads();
    if (ty == 0) {
        float4 s = red[tx][0];
#pragma unroll
        for (int j = 1; j < 32; ++j) {
            const float4 v = red[tx][j];
            s.x += v.x; s.y += v.y; s.z += v.z; s.w += v.w;
        }
        ((float4*)x_attn)[f] = s;
    }
}

// ---------------- launch ----------------
extern "C" void kernel_launch(void* const* d_in, const int* in_sizes, int n_in,
                              void* d_out, int out_size, void* d_ws, size_t ws_size,
                              hipStream_t stream) {
    const int*   tok    = (const int*)d_in[0];
    const int*   pos    = (const int*)d_in[1];
    const float* keys   = (const float*)d_in[2];
    const float* values = (const float*)d_in[3];
    const float* wte    = (const float*)d_in[4];
    const float* wpe    = (const float*)d_in[5];
    const float* wq     = (const float*)d_in[6];
    const float* wk     = (const float*)d_in[7];
    const float* wv     = (const float*)d_in[8];
    const float* wo     = (const float*)d_in[9];
    const float* w1     = (const float*)d_in[10];
    const float* w2     = (const float*)d_in[11];
    const float* lm_w   = (const float*)d_in[12];
    float* out = (float*)d_out;

    float* ws = (float*)d_ws;
    float* x_res1  = ws;            // 2048
    float* q       = ws + 4096;     // 2048
    float* k       = ws + 6144;     // 2048
    float* v       = ws + 8192;     // 2048
    float* x_attn  = ws + 10240;    // 2048
    float* x2      = ws + 12288;    // 2048
    float* sm      = ws + 14336;    // 32 (head max + inv-sum)
    float* hbuf    = ws + 16384;    // 8192
    float* x3      = ws + 24576;    // 2048
    float* att     = ws + 26624;    // 16*8224 = 131584
    float* part    = ws + 158208;   // 513*2048 = 1050624  (total ~4.84 MB)

    qkv_fused_kernel<<<1536, 256, 0, stream>>>(tok, pos, wte, wpe, wq, wk, wv,
                                               x_res1, q, k, v);

    attn_scores_kernel<<<(TT + 3) / 4, 256, 0, stream>>>(keys, k, q, att);
    softmax_stats_kernel<<<NHEAD, 1024, 0, stream>>>(att, sm);
    attn_av_kernel<<<NCHUNK, 256, 0, stream>>>(values, v, att, sm, part);
    attn_reduce_kernel<<<64, 256, 0, stream>>>(part, x_attn);

    matvec_kernel<E4, false, true><<<512, 256, 0, stream>>>(wo, x_attn, x_res1, x2, E_DIM);

    rms_matvec_kernel<E4, true><<<2048, 256, 0, stream>>>(w1, x2, hbuf, 4 * E_DIM);
    matvec_kernel<4 * E4, false, true><<<512, 256, 0, stream>>>(w2, hbuf, x2, x3, E_DIM);

    matvec_kernel<E4, false, false><<<(VOCAB + 3) / 4, 256, 0, stream>>>(lm_w, x3, nullptr, out, VOCAB);
}